// Round 9
// baseline (234.800 us; speedup 1.0000x reference)
//
#include <hip/hip_runtime.h>
#include <hip/hip_bf16.h>
#include <stdint.h>

// Problem constants
#define L_DIM 1024
#define C_DIM 512       // channels (elements)
#define CB4 256         // fp4 row stride in BYTES (512 elems * 4 bit)
#define N_BATCH 32
#define M_NEG 4096
#define NROWS (N_BATCH * L_DIM) // 32768

typedef float f32x4 __attribute__((ext_vector_type(4)));
typedef int i32x4 __attribute__((ext_vector_type(4)));
typedef int i32x8 __attribute__((ext_vector_type(8)));

// E stored as fp4 e2m1 scaled by 32 (clip at |x|=0.1875 ~ 4.3 sigma);
// e8m0 scale 122 (=2^-5) on both MFMA operands gives exact 1/1024 comp.
#define E4_SCALE 32.0f
#define MX_SCALE 122
#define FMT_FP4 4

// fp4 e2m1 round-to-nearest encode of pre-scaled value.
__device__ __forceinline__ uint32_t fp4_enc(float x) {
  const uint32_t s = (__float_as_uint(x) >> 31) << 3;
  const float a = fabsf(x);
  uint32_t c;
  c = a < 0.25f ? 0u
    : a < 0.75f ? 1u
    : a < 1.25f ? 2u
    : a < 1.75f ? 3u
    : a < 2.5f  ? 4u
    : a < 3.5f  ? 5u
    : a < 5.0f  ? 6u : 7u;
  return s | c;
}

// ---------------------------------------------------------------------------
// Kernel 1: row-wise L2 normalize fp32 [32768, 512] -> fp4 e2m1 (x32 scaled).
// Blocks 0..255 also zero the 256 KB rowsum+simpos accumulators; block 0
// zeroes the loss scalar (enables multi-block atomic finalize).
// ---------------------------------------------------------------------------
__global__ __launch_bounds__(256) void k_normalize(const float* __restrict__ emb,
                                                   uint8_t* __restrict__ out,
                                                   float* __restrict__ zerobuf,
                                                   float* __restrict__ loss_out) {
  if (blockIdx.x < 256) zerobuf[blockIdx.x * 256 + threadIdx.x] = 0.0f;
  if (blockIdx.x == 0 && threadIdx.x == 0) loss_out[0] = 0.0f;
  const int lane = threadIdx.x & 63;
  const int wave = threadIdx.x >> 6;
  const long row = (long)blockIdx.x * 4 + wave;
  const float4* src = (const float4*)(emb + row * C_DIM);
  float4 v0 = src[2 * lane];
  float4 v1 = src[2 * lane + 1];
  float ss = v0.x * v0.x + v0.y * v0.y + v0.z * v0.z + v0.w * v0.w +
             v1.x * v1.x + v1.y * v1.y + v1.z * v1.z + v1.w * v1.w;
#pragma unroll
  for (int off = 1; off < 64; off <<= 1) ss += __shfl_xor(ss, off, 64);
  const float s = E4_SCALE / fmaxf(sqrtf(ss), 1e-12f);
  uint32_t pk = fp4_enc(v0.x * s)        | (fp4_enc(v0.y * s) << 4) |
                (fp4_enc(v0.z * s) << 8) | (fp4_enc(v0.w * s) << 12) |
                (fp4_enc(v1.x * s) << 16)| (fp4_enc(v1.y * s) << 20) |
                (fp4_enc(v1.z * s) << 24)| (fp4_enc(v1.w * s) << 28);
  ((uint32_t*)(out + row * CB4))[lane] = pk;
}

// ---------------------------------------------------------------------------
// Kernel 2 (FUSED): one 5120-block dispatch, both GEMMs, NO LDS STAGING.
// Each lane loads its MFMA fragments directly global->register
// (global_load_dwordx4, loop-invariant base + ks*64 immediate offset).
// -> zero K-loop barriers, zero vmcnt(0) drains; compiler free to
//    interleave MFMA with loads using fine-grained vmcnt (AITER pattern).
// Relies on R8's XCD swizzle keeping tiles L2-resident:
//   mode 0 (bid>=1024): t=bid-1024; xcd=t&7, slot=t>>3;
//       rowTile=xcd*16+(slot&15), colTile=slot>>4  (~2 MB/XCD unique).
//   mode 1 (bid<1024): xcd=bid&7; n=xcd*4+(slot&3); inner=slot>>2.
// Fragment map (16x16x128 fp4): lane=c16+16q holds row c16, k-bytes
// [q*16, q*16+16) of the 64 B kstep slice; byte = row*256 + ks*64 + q*16.
// LDS (40960 B) used by the epilogue only.
// ---------------------------------------------------------------------------
__global__ __launch_bounds__(256, 2) void k_gemm_fused(
    const uint8_t* __restrict__ E4, const int* __restrict__ idx,
    const float* __restrict__ W, float* __restrict__ rowsum,
    float* __restrict__ simpos) {
  __shared__ __align__(16) unsigned char smem_raw[40960];

  const int tid = threadIdx.x;
  const int lane = tid & 63;
  const int wave = tid >> 6;
  const int wm = wave >> 1, wn = wave & 1;
  const int q = lane >> 4, c16 = lane & 15;

  const int bid = blockIdx.x;
  const bool is0 = bid >= 1024;
  long rowBase, colBase, n = 0;
  if (is0) {
    const int t = bid - 1024;
    const int xcd = t & 7, slot = t >> 3;
    rowBase = (long)(xcd * 16 + (slot & 15)) * 256;
    colBase = (long)(slot >> 4) * 128;
  } else {
    const int xcd = bid & 7, slot = bid >> 3;
    n = xcd * 4 + (slot & 3);
    const int inner = slot >> 2;          // 0..31
    rowBase = (long)(inner & 3) * 256;
    colBase = (long)(inner >> 2) * 128;
  }
  const long aBase = is0 ? rowBase : n * L_DIM + rowBase;

  // Loop-invariant fragment base pointers (this lane's row + q-slice).
  const uint8_t* aptr[8];
#pragma unroll
  for (int i = 0; i < 8; ++i)
    aptr[i] = E4 + (aBase + wm * 128 + i * 16 + c16) * CB4 + q * 16;
  const uint8_t* bptr[4];
#pragma unroll
  for (int j = 0; j < 4; ++j) {
    const int brow = wn * 64 + j * 16 + c16;
    const long bRow = is0 ? (long)idx[colBase + brow] : n * L_DIM + colBase + brow;
    bptr[j] = E4 + bRow * CB4 + q * 16;
  }

  f32x4 acc[8][4] = {};
  const i32x4 zz = {0, 0, 0, 0};

#pragma unroll
  for (int ks = 0; ks < 4; ++ks) {
    i32x4 a4[8];
    i32x4 b4[4];
#pragma unroll
    for (int j = 0; j < 4; ++j) b4[j] = *(const i32x4*)(bptr[j] + ks * 64);
#pragma unroll
    for (int i = 0; i < 8; ++i) a4[i] = *(const i32x4*)(aptr[i] + ks * 64);
    i32x8 bfr[4];
#pragma unroll
    for (int j = 0; j < 4; ++j)
      bfr[j] = __builtin_shufflevector(b4[j], zz, 0, 1, 2, 3, 4, 5, 6, 7);
#pragma unroll
    for (int i = 0; i < 8; ++i) {
      i32x8 af = __builtin_shufflevector(a4[i], zz, 0, 1, 2, 3, 4, 5, 6, 7);
#pragma unroll
      for (int j = 0; j < 4; ++j)
        acc[i][j] = __builtin_amdgcn_mfma_scale_f32_16x16x128_f8f6f4(
            af, bfr[j], acc[i][j], FMT_FP4, FMT_FP4,
            0, MX_SCALE, 0, MX_SCALE);
    }
  }

  // Epilogue. C/D layout: col = c16, row = q*4 + reg (per 16x16 tile).
  if (is0) {
    float* S = (float*)smem_raw;  // [4 waves][128 rows][pad 20] = 40960 B
#pragma unroll
    for (int i = 0; i < 8; ++i)
#pragma unroll
      for (int r = 0; r < 4; ++r) {
        const float s = __expf(acc[i][0][r]) + __expf(acc[i][1][r]) +
                        __expf(acc[i][2][r]) + __expf(acc[i][3][r]);
        S[wave * 2560 + (i * 16 + q * 4 + r) * 20 + c16] = s;
      }
    __syncthreads();
    {
      const int wmg = tid >> 7, rs = tid & 127;  // global row = rowBase + tid
      const float4* p0 = (const float4*)(S + (wmg * 2 + 0) * 2560 + rs * 20);
      const float4* p1 = (const float4*)(S + (wmg * 2 + 1) * 2560 + rs * 20);
      float4 t0 = p0[0], t1 = p0[1], t2 = p0[2], t3 = p0[3];
      float4 u0 = p1[0], u1 = p1[1], u2 = p1[2], u3 = p1[3];
      float v = t0.x + t0.y + t0.z + t0.w + t1.x + t1.y + t1.z + t1.w +
                t2.x + t2.y + t2.z + t2.w + t3.x + t3.y + t3.z + t3.w +
                u0.x + u0.y + u0.z + u0.w + u1.x + u1.y + u1.z + u1.w +
                u2.x + u2.y + u2.z + u2.w + u3.x + u3.y + u3.z + u3.w;
      atomicAdd(&rowsum[rowBase + tid], v);
    }
  } else {
    float* G = (float*)smem_raw;  // [64 rows][pad 132] fp32 = 33792 B
#pragma unroll
    for (int p = 0; p < 4; ++p) {
      if (wm == (p >> 1)) {
        const int ib = (p & 1) * 4;
#pragma unroll
        for (int ii = 0; ii < 4; ++ii)
#pragma unroll
          for (int j = 0; j < 4; ++j)
#pragma unroll
            for (int r = 0; r < 4; ++r)
              G[(ii * 16 + q * 4 + r) * 132 + wn * 64 + j * 16 + c16] =
                  acc[ib + ii][j][r];
      }
      __syncthreads();
      {
        const int rr = tid >> 2;    // 0..63
        const int chunk = tid & 3;  // strided 16B-chunks (bank-uniform)
        const long krow = rowBase + p * 64 + rr;
        float v = 0.0f;
#pragma unroll
        for (int u = 0; u < 8; ++u) {
          const float4 g = *(const float4*)(G + rr * 132 + u * 16 + chunk * 4);
          const float4 w4 =
              *(const float4*)(W + krow * L_DIM + colBase + u * 16 + chunk * 4);
          v += g.x * w4.x + g.y * w4.y + g.z * w4.z + g.w * w4.w;
        }
        v += __shfl_xor(v, 1, 64);
        v += __shfl_xor(v, 2, 64);
        if (chunk == 0) atomicAdd(&simpos[n * L_DIM + krow], v);
      }
      __syncthreads();
    }
  }
}

// ---------------------------------------------------------------------------
// Kernel 3: 128-block finalize; out[0] pre-zeroed by k_normalize.
// loss = mean over rows of log(rowsum_neg + exp(simpos)) - simpos
// ---------------------------------------------------------------------------
__global__ __launch_bounds__(256) void k_finalize(const float* __restrict__ rowsum,
                                                  const float* __restrict__ simpos,
                                                  float* __restrict__ out) {
  const int gid = blockIdx.x * 256 + threadIdx.x;  // one row per thread
  const float sp = simpos[gid];
  float v = __logf(rowsum[gid] + __expf(sp)) - sp;
#pragma unroll
  for (int off = 1; off < 64; off <<= 1) v += __shfl_xor(v, off, 64);
  __shared__ float ws[4];
  if ((threadIdx.x & 63) == 0) ws[threadIdx.x >> 6] = v;
  __syncthreads();
  if (threadIdx.x == 0)
    atomicAdd(out, (ws[0] + ws[1] + ws[2] + ws[3]) * (1.0f / (float)NROWS));
}

// ---------------------------------------------------------------------------
// Workspace layout (bytes):
//   [0,       8388608)  E fp4 [32768, 256 B]   (x32 scaled e2m1)
//   [8388608, 8519680)  rowsum fp32 [32768]
//   [8519680, 8650752)  simpos fp32 [32768]    (contiguous with rowsum)
// ---------------------------------------------------------------------------
extern "C" void kernel_launch(void* const* d_in, const int* in_sizes, int n_in,
                              void* d_out, int out_size, void* d_ws, size_t ws_size,
                              hipStream_t stream) {
  const float* emb = (const float*)d_in[0];
  const float* weight = (const float*)d_in[1];
  const int* negidx = (const int*)d_in[2];
  float* out = (float*)d_out;
  char* ws = (char*)d_ws;

  uint8_t* E4 = (uint8_t*)ws;
  float* rowsum = (float*)(ws + 8388608);
  float* simpos = (float*)(ws + 8519680);

  k_normalize<<<NROWS / 4, 256, 0, stream>>>(emb, E4, rowsum, out);
  k_gemm_fused<<<5120, 256, 0, stream>>>(E4, negidx, weight, rowsum, simpos);
  k_finalize<<<NROWS / 256, 256, 0, stream>>>(rowsum, simpos, out);
}

// Round 10
// 169.126 us; speedup vs baseline: 1.3883x; 1.3883x over previous
//
#include <hip/hip_runtime.h>
#include <hip/hip_bf16.h>
#include <stdint.h>

// Problem constants
#define L_DIM 1024
#define C_DIM 512       // channels (elements)
#define CB4 256         // fp4 row stride in BYTES (512 elems * 4 bit)
#define N_BATCH 32
#define M_NEG 4096
#define NROWS (N_BATCH * L_DIM) // 32768

typedef float f32x4 __attribute__((ext_vector_type(4)));
typedef int i32x4 __attribute__((ext_vector_type(4)));
typedef int i32x8 __attribute__((ext_vector_type(8)));

// E stored as fp4 e2m1 scaled by 32 (clip at |x|=0.1875 ~ 4.3 sigma);
// e8m0 scale 122 (=2^-5) on both MFMA operands gives exact 1/1024 comp.
#define E4_SCALE 32.0f
#define MX_SCALE 122
#define FMT_FP4 4

__device__ __forceinline__ void gl_lds16(const uint8_t* g, uint8_t* l) {
  __builtin_amdgcn_global_load_lds(
      (const __attribute__((address_space(1))) void*)g,
      (__attribute__((address_space(3))) void*)l, 16, 0, 0);
}

// fp4 e2m1 round-to-nearest encode of pre-scaled value.
__device__ __forceinline__ uint32_t fp4_enc(float x) {
  const uint32_t s = (__float_as_uint(x) >> 31) << 3;
  const float a = fabsf(x);
  uint32_t c;
  c = a < 0.25f ? 0u
    : a < 0.75f ? 1u
    : a < 1.25f ? 2u
    : a < 1.75f ? 3u
    : a < 2.5f  ? 4u
    : a < 3.5f  ? 5u
    : a < 5.0f  ? 6u : 7u;
  return s | c;
}

// fp4 operand tuple: hardware reads only v[0:3] for FMT_FP4, so the upper
// half is UNDEF (-1), not zero -> no v_mov tuple-build (R8's zero-extend
// cost ~1500 movs/block = the measured 35% VALUBusy).
__device__ __forceinline__ i32x8 fp4_op(i32x4 d) {
  return __builtin_shufflevector(d, d, 0, 1, 2, 3, -1, -1, -1, -1);
}

// ---------------------------------------------------------------------------
// Kernel 1: row-wise L2 normalize fp32 [32768, 512] -> fp4 e2m1 (x32 scaled).
// Blocks 0..255 also zero the 256 KB rowsum+simpos accumulators; block 0
// zeroes the loss scalar (enables multi-block atomic finalize).
// ---------------------------------------------------------------------------
__global__ __launch_bounds__(256) void k_normalize(const float* __restrict__ emb,
                                                   uint8_t* __restrict__ out,
                                                   float* __restrict__ zerobuf,
                                                   float* __restrict__ loss_out) {
  if (blockIdx.x < 256) zerobuf[blockIdx.x * 256 + threadIdx.x] = 0.0f;
  if (blockIdx.x == 0 && threadIdx.x == 0) loss_out[0] = 0.0f;
  const int lane = threadIdx.x & 63;
  const int wave = threadIdx.x >> 6;
  const long row = (long)blockIdx.x * 4 + wave;
  const float4* src = (const float4*)(emb + row * C_DIM);
  float4 v0 = src[2 * lane];
  float4 v1 = src[2 * lane + 1];
  float ss = v0.x * v0.x + v0.y * v0.y + v0.z * v0.z + v0.w * v0.w +
             v1.x * v1.x + v1.y * v1.y + v1.z * v1.z + v1.w * v1.w;
#pragma unroll
  for (int off = 1; off < 64; off <<= 1) ss += __shfl_xor(ss, off, 64);
  const float s = E4_SCALE / fmaxf(sqrtf(ss), 1e-12f);
  uint32_t pk = fp4_enc(v0.x * s)        | (fp4_enc(v0.y * s) << 4) |
                (fp4_enc(v0.z * s) << 8) | (fp4_enc(v0.w * s) << 12) |
                (fp4_enc(v1.x * s) << 16)| (fp4_enc(v1.y * s) << 20) |
                (fp4_enc(v1.z * s) << 24)| (fp4_enc(v1.w * s) << 28);
  ((uint32_t*)(out + row * CB4))[lane] = pk;
}

// ---------------------------------------------------------------------------
// Kernel 2 (FUSED): one 5120-block dispatch covering both GEMMs.
// R8 structure (global_load_lds staging = the coalescer; R9's direct
// per-lane loads scattered 16 cache lines/instr and regressed 1.8x).
// XCD-AWARE SWIZZLE (dispatch round-robin xcd ~= bid&7):
//   mode 0 (bid>=1024): t=bid-1024; xcd=t&7, slot=t>>3;
//       rowTile=xcd*16+(slot&15), colTile=slot>>4  (~2 MB/XCD unique).
//   mode 1 (bid<1024): xcd=bid&7; n=xcd*4+(slot&3); inner=slot>>2.
// 256x128 MX-fp4 K-loop: mfma_scale 16x16x128 fp4 (K=128/inst, 4 ksteps).
// LDS: A [256][64B] + B [128][64B] = 24 KB, XOR-swizzled in 16 B groups.
// Operand tuples carry UNDEF upper halves (fp4 reads 4 regs only).
// ---------------------------------------------------------------------------
__global__ __launch_bounds__(256, 2) void k_gemm_fused(
    const uint8_t* __restrict__ E4, const int* __restrict__ idx,
    const float* __restrict__ W, float* __restrict__ rowsum,
    float* __restrict__ simpos) {
  __shared__ __align__(16) unsigned char smem_raw[40960];
  uint8_t* sA = (uint8_t*)smem_raw;          // [256][64] fp4 = 16 KB
  uint8_t* sB = sA + 256 * 64;               // [128][64] fp4 =  8 KB

  const int tid = threadIdx.x;
  const int lane = tid & 63;
  const int wave = tid >> 6;
  const int wm = wave >> 1, wn = wave & 1;
  const int q = lane >> 4, c16 = lane & 15;

  const int bid = blockIdx.x;
  const bool is0 = bid >= 1024;
  long rowBase, colBase, n = 0;
  if (is0) {
    const int t = bid - 1024;
    const int xcd = t & 7, slot = t >> 3;
    rowBase = (long)(xcd * 16 + (slot & 15)) * 256;
    colBase = (long)(slot >> 4) * 128;
  } else {
    const int xcd = bid & 7, slot = bid >> 3;
    n = xcd * 4 + (slot & 3);
    const int inner = slot >> 2;          // 0..31
    rowBase = (long)(inner & 3) * 256;
    colBase = (long)(inner >> 2) * 128;
  }
  const long aBase = is0 ? rowBase : n * L_DIM + rowBase;

  // Per-thread staging source byte-offsets (swizzle folded in).
  long offA[4], offB[2];
#pragma unroll
  for (int r = 0; r < 4; ++r) {
    const int c = r * 256 + tid;          // A 16B-chunk 0..1023
    const int rw = c >> 2, cb = c & 3;    // row 0..255, group 0..3
    offA[r] = (aBase + rw) * CB4 + (cb ^ (rw & 3)) * 16;
  }
#pragma unroll
  for (int r = 0; r < 2; ++r) {
    const int c = r * 256 + tid;          // B 16B-chunk 0..511
    const int rw = c >> 2, cb = c & 3;    // row 0..127
    const long bRow = is0 ? (long)idx[colBase + rw] : n * L_DIM + colBase + rw;
    offB[r] = bRow * CB4 + (cb ^ (rw & 3)) * 16;
  }

  f32x4 acc[8][4] = {};

#pragma unroll
  for (int ks = 0; ks < CB4; ks += 64) {
#pragma unroll
    for (int r = 0; r < 4; ++r)
      gl_lds16(E4 + offA[r] + ks, sA + (r * 256 + tid) * 16);
#pragma unroll
    for (int r = 0; r < 2; ++r)
      gl_lds16(E4 + offB[r] + ks, sB + (r * 256 + tid) * 16);
    __syncthreads();
    i32x8 bfr[4];
#pragma unroll
    for (int j = 0; j < 4; ++j) {
      const int row = wn * 64 + j * 16 + c16;
      bfr[j] = fp4_op(*(const i32x4*)(sB + row * 64 + (q ^ (row & 3)) * 16));
    }
#pragma unroll
    for (int i = 0; i < 8; ++i) {
      const int row = wm * 128 + i * 16 + c16;
      i32x8 af =
          fp4_op(*(const i32x4*)(sA + row * 64 + (q ^ (row & 3)) * 16));
#pragma unroll
      for (int j = 0; j < 4; ++j)
        acc[i][j] = __builtin_amdgcn_mfma_scale_f32_16x16x128_f8f6f4(
            af, bfr[j], acc[i][j], FMT_FP4, FMT_FP4,
            0, MX_SCALE, 0, MX_SCALE);
    }
    __syncthreads();
  }

  // Epilogue. C/D layout: col = c16, row = q*4 + reg (per 16x16 tile).
  if (is0) {
    float* S = (float*)smem_raw;  // [4 waves][128 rows][pad 20] = 40960 B
#pragma unroll
    for (int i = 0; i < 8; ++i)
#pragma unroll
      for (int r = 0; r < 4; ++r) {
        const float s = __expf(acc[i][0][r]) + __expf(acc[i][1][r]) +
                        __expf(acc[i][2][r]) + __expf(acc[i][3][r]);
        S[wave * 2560 + (i * 16 + q * 4 + r) * 20 + c16] = s;
      }
    __syncthreads();
    {
      const int wmg = tid >> 7, rs = tid & 127;  // global row = rowBase + tid
      const float4* p0 = (const float4*)(S + (wmg * 2 + 0) * 2560 + rs * 20);
      const float4* p1 = (const float4*)(S + (wmg * 2 + 1) * 2560 + rs * 20);
      float4 t0 = p0[0], t1 = p0[1], t2 = p0[2], t3 = p0[3];
      float4 u0 = p1[0], u1 = p1[1], u2 = p1[2], u3 = p1[3];
      float v = t0.x + t0.y + t0.z + t0.w + t1.x + t1.y + t1.z + t1.w +
                t2.x + t2.y + t2.z + t2.w + t3.x + t3.y + t3.z + t3.w +
                u0.x + u0.y + u0.z + u0.w + u1.x + u1.y + u1.z + u1.w +
                u2.x + u2.y + u2.z + u2.w + u3.x + u3.y + u3.z + u3.w;
      atomicAdd(&rowsum[rowBase + tid], v);
    }
  } else {
    float* G = (float*)smem_raw;  // [64 rows][pad 132] fp32 = 33792 B
#pragma unroll
    for (int p = 0; p < 4; ++p) {
      if (wm == (p >> 1)) {
        const int ib = (p & 1) * 4;
#pragma unroll
        for (int ii = 0; ii < 4; ++ii)
#pragma unroll
          for (int j = 0; j < 4; ++j)
#pragma unroll
            for (int r = 0; r < 4; ++r)
              G[(ii * 16 + q * 4 + r) * 132 + wn * 64 + j * 16 + c16] =
                  acc[ib + ii][j][r];
      }
      __syncthreads();
      {
        const int rr = tid >> 2;    // 0..63
        const int chunk = tid & 3;  // strided 16B-chunks (bank-uniform)
        const long krow = rowBase + p * 64 + rr;
        float v = 0.0f;
#pragma unroll
        for (int u = 0; u < 8; ++u) {
          const float4 g = *(const float4*)(G + rr * 132 + u * 16 + chunk * 4);
          const float4 w4 =
              *(const float4*)(W + krow * L_DIM + colBase + u * 16 + chunk * 4);
          v += g.x * w4.x + g.y * w4.y + g.z * w4.z + g.w * w4.w;
        }
        v += __shfl_xor(v, 1, 64);
        v += __shfl_xor(v, 2, 64);
        if (chunk == 0) atomicAdd(&simpos[n * L_DIM + krow], v);
      }
      __syncthreads();
    }
  }
}

// ---------------------------------------------------------------------------
// Kernel 3: 128-block finalize; out[0] pre-zeroed by k_normalize.
// loss = mean over rows of log(rowsum_neg + exp(simpos)) - simpos
// ---------------------------------------------------------------------------
__global__ __launch_bounds__(256) void k_finalize(const float* __restrict__ rowsum,
                                                  const float* __restrict__ simpos,
                                                  float* __restrict__ out) {
  const int gid = blockIdx.x * 256 + threadIdx.x;  // one row per thread
  const float sp = simpos[gid];
  float v = __logf(rowsum[gid] + __expf(sp)) - sp;
#pragma unroll
  for (int off = 1; off < 64; off <<= 1) v += __shfl_xor(v, off, 64);
  __shared__ float ws[4];
  if ((threadIdx.x & 63) == 0) ws[threadIdx.x >> 6] = v;
  __syncthreads();
  if (threadIdx.x == 0)
    atomicAdd(out, (ws[0] + ws[1] + ws[2] + ws[3]) * (1.0f / (float)NROWS));
}

// ---------------------------------------------------------------------------
// Workspace layout (bytes):
//   [0,       8388608)  E fp4 [32768, 256 B]   (x32 scaled e2m1)
//   [8388608, 8519680)  rowsum fp32 [32768]
//   [8519680, 8650752)  simpos fp32 [32768]    (contiguous with rowsum)
// ---------------------------------------------------------------------------
extern "C" void kernel_launch(void* const* d_in, const int* in_sizes, int n_in,
                              void* d_out, int out_size, void* d_ws, size_t ws_size,
                              hipStream_t stream) {
  const float* emb = (const float*)d_in[0];
  const float* weight = (const float*)d_in[1];
  const int* negidx = (const int*)d_in[2];
  float* out = (float*)d_out;
  char* ws = (char*)d_ws;

  uint8_t* E4 = (uint8_t*)ws;
  float* rowsum = (float*)(ws + 8388608);
  float* simpos = (float*)(ws + 8519680);

  k_normalize<<<NROWS / 4, 256, 0, stream>>>(emb, E4, rowsum, out);
  k_gemm_fused<<<5120, 256, 0, stream>>>(E4, negidx, weight, rowsum, simpos);
  k_finalize<<<NROWS / 256, 256, 0, stream>>>(rowsum, simpos, out);
}